// Round 4
// baseline (739.802 us; speedup 1.0000x reference)
//
#include <hip/hip_runtime.h>
#include <math.h>

namespace {

typedef __attribute__((ext_vector_type(8))) short short8;    // 8 bf16 = 4 VGPRs
typedef __attribute__((ext_vector_type(4))) short short4b;   // 4 bf16 = 8 B
typedef __attribute__((ext_vector_type(4))) float floatx4;   // MFMA C/D frag

constexpr int B_ = 2;
constexpr int S_ = 2048;
constexpr int DM_ = 1024;
constexpr int NH_ = 16;
constexpr int HD_ = 64;

// fp32 -> bf16 round-to-nearest-even
__device__ inline unsigned short f2bf(float f) {
  unsigned u = __builtin_bit_cast(unsigned, f);
  u += 0x7fffu + ((u >> 16) & 1u);
  return (unsigned short)(u >> 16);
}

// async global->LDS, 16B per lane; lane i lands at lds + i*16 (wave-uniform base)
__device__ inline void gl2lds16(const unsigned short* g, unsigned short* l) {
  __builtin_amdgcn_global_load_lds(
      (const __attribute__((address_space(1))) unsigned int*)g,
      (__attribute__((address_space(3))) unsigned int*)l, 16, 0, 0);
}

__device__ inline void rope_param(int p, int* axis, float* invf) {
  int j, dseg;
  if (p < 10)      { *axis = 0; j = p;      dseg = 20; }
  else if (p < 20) { *axis = 1; j = p - 10; dseg = 20; }
  else             { *axis = 2; j = p - 20; dseg = 24; }
  // 10000^(-2j/dseg) = exp(-(2j/dseg)*ln(1e4))
  *invf = __expf(-(2.0f * (float)j / (float)dseg) * 9.210340371976184f);
}

// ---------------------------------------------------------------------------
__global__ void cvt_bf16(const float* __restrict__ in,
                         unsigned short* __restrict__ out, int n8) {
  const int i = blockIdx.x * blockDim.x + threadIdx.x;
  if (i >= n8) return;
  const float4 a = ((const float4*)in)[i * 2];
  const float4 b = ((const float4*)in)[i * 2 + 1];
  short8 v;
  v[0] = (short)f2bf(a.x); v[1] = (short)f2bf(a.y);
  v[2] = (short)f2bf(a.z); v[3] = (short)f2bf(a.w);
  v[4] = (short)f2bf(b.x); v[5] = (short)f2bf(b.y);
  v[6] = (short)f2bf(b.z); v[7] = (short)f2bf(b.w);
  ((short8*)out)[i] = v;
}

// ---------------------------------------------------------------------------
__global__ void lengths_kernel(const unsigned char* __restrict__ mask,
                               int* __restrict__ lengths) {
  const int es1 = (mask[1] != 0);  // byte-1 nonzero => 1-byte bool storage
  const int b = blockIdx.x;
  __shared__ int cnt;
  if (threadIdx.x == 0) cnt = 0;
  __syncthreads();
  int local = 0;
  for (int s = threadIdx.x; s < S_; s += blockDim.x) {
    bool nz;
    if (es1) nz = mask[b * S_ + s] != 0;
    else     nz = ((const unsigned int*)mask)[b * S_ + s] != 0;
    local += nz ? 1 : 0;
  }
  atomicAdd(&cnt, local);
  __syncthreads();
  if (threadIdx.x == 0) lengths[b] = cnt;
}

// ---------------------------------------------------------------------------
// QKV GEMM (bf16 MFMA): C[m][n] = sum_k A[m][k] * W[n][k]
// M=4096, N=3072, K=1024. 128x128 tile, BK=32, 4 waves each 64x64.
// Epilogue: RoPE applied IN REGISTERS on the fp32 accumulators (pair partner
// via shfl_xor(v,1); single bf16 rounding — round-3's post-LDS RoPE double-
// rounded and doubled absmax). The LDS round-trip then only re-lays-out final
// bf16 bits so all global stores are >=64B-contiguous runs (round-2 profile:
// 2-byte scatters caused 1.4 GB HBM writes vs 25 MB ideal).
// Outputs: Q,K:(B,NH,S,64) bf16 (q pre-scaled by 0.125), V^T:(B,NH,64,S) bf16.
// ---------------------------------------------------------------------------
__global__ __launch_bounds__(256) void qkv_gemm(
    const unsigned short* __restrict__ A, const unsigned short* __restrict__ W,
    const int* __restrict__ pos_xyz,
    unsigned short* __restrict__ Qb, unsigned short* __restrict__ Kb,
    unsigned short* __restrict__ Vtb) {
  __shared__ __align__(16) unsigned short As[128 * 32];
  __shared__ __align__(16) unsigned short Bs[128 * 32];
  __shared__ __align__(16) unsigned short Ts[4][64 * 36];  // wave-private
  const int m0 = blockIdx.y * 128, n0 = blockIdx.x * 128;
  const int w = threadIdx.x >> 6, lane = threadIdx.x & 63;
  const int lm = lane & 15, q4 = lane >> 4;
  const int srow = w * 32;                  // this wave's staging rows
  const int r_in = lane >> 2, c_in = (lane & 3) * 8;
  const int wr = (w >> 1) * 64, wc = (w & 1) * 64;
  floatx4 acc[4][4];
  const floatx4 z4 = {0.f, 0.f, 0.f, 0.f};
#pragma unroll
  for (int i = 0; i < 4; i++)
#pragma unroll
    for (int j = 0; j < 4; j++) acc[i][j] = z4;

  for (int k0 = 0; k0 < DM_; k0 += 32) {
    gl2lds16(A + (size_t)(m0 + srow + r_in) * DM_ + k0 + c_in, As + srow * 32);
    gl2lds16(A + (size_t)(m0 + srow + 16 + r_in) * DM_ + k0 + c_in,
             As + (srow + 16) * 32);
    gl2lds16(W + (size_t)(n0 + srow + r_in) * DM_ + k0 + c_in, Bs + srow * 32);
    gl2lds16(W + (size_t)(n0 + srow + 16 + r_in) * DM_ + k0 + c_in,
             Bs + (srow + 16) * 32);
    __syncthreads();
    short8 af[4], bf[4];
#pragma unroll
    for (int t = 0; t < 4; t++)
      af[t] = *(const short8*)(As + (wr + t * 16 + lm) * 32 + q4 * 8);
#pragma unroll
    for (int t = 0; t < 4; t++)
      bf[t] = *(const short8*)(Bs + (wc + t * 16 + lm) * 32 + q4 * 8);
#pragma unroll
    for (int i = 0; i < 4; i++)
#pragma unroll
      for (int j = 0; j < 4; j++)
        acc[i][j] =
            __builtin_amdgcn_mfma_f32_16x16x32_bf16(af[i], bf[j], acc[i][j],
                                                    0, 0, 0);
    __syncthreads();
  }

  // ---- epilogue (wave-private Ts; DS ops are in-order per wave)
  const int which = n0 >> 10;                      // block-uniform
  const int hU = ((n0 + wc) & 1023) >> 6;          // head, wave-uniform
  const int biU = (m0 + wr) >> 11;                 // batch, wave-uniform
  const int si0 = (m0 + wr) & (S_ - 1);            // wave's first seq row
  unsigned short* ts = Ts[w];
  const int rgrp = lane >> 3;                      // 0..7 (row group)
  const int cgrp = (lane & 7) * 4;                 // col offset (halfwords)

  if (which == 2) {
    // V: LDS [d:64][m_half:32+pad] then coalesced V^T stores (64B runs)
#pragma unroll
    for (int h2 = 0; h2 < 2; h2++) {
#pragma unroll
      for (int nt = 0; nt < 4; nt++)
#pragma unroll
        for (int mh = 0; mh < 2; mh++) {
          const int mt = h2 * 2 + mh;
#pragma unroll
          for (int r = 0; r < 4; r++)
            ts[(nt * 16 + lm) * 36 + mh * 16 + q4 * 4 + r] =
                f2bf(acc[mt][nt][r]);
        }
#pragma unroll
      for (int it = 0; it < 8; it++) {
        const int d = it * 8 + rgrp;
        const short4b v = *(const short4b*)(ts + d * 36 + cgrp);
        const int si = si0 + h2 * 32 + cgrp;
        *(short4b*)(Vtb + ((size_t)(biU * NH_ + hU) * HD_ + d) * S_ + si) = v;
      }
    }
  } else {
    // Q/K: RoPE on fp32 accs in D-layout (partner = adjacent lane), single
    // f2bf, then LDS [m:64][d_half:32+pad] re-layout and coalesced stores.
    unsigned short* Dst = (which == 0) ? Qb : Kb;
    const float osc = (which == 0) ? 0.125f : 1.0f;  // q pre-scaled
#pragma unroll
    for (int h2 = 0; h2 < 2; h2++) {
#pragma unroll
      for (int nh = 0; nh < 2; nh++) {
        const int nt = h2 * 2 + nh;
        const int d = nt * 16 + lm;
        int axis;
        float invf;
        rope_param(d >> 1, &axis, &invf);
#pragma unroll
        for (int mt = 0; mt < 4; mt++)
#pragma unroll
          for (int r = 0; r < 4; r++) {
            const int si = si0 + mt * 16 + q4 * 4 + r;
            const float v = acc[mt][nt][r];
            const float vp = __shfl_xor(v, 1);  // pair partner (d^1)
            const int pos = pos_xyz[((size_t)biU * S_ + si) * 3 + axis];
            float sn, cs;
            sincosf((float)pos * invf, &sn, &cs);
            const float y =
                (d & 1) ? fmaf(v, cs, vp * sn) : fmaf(v, cs, -vp * sn);
            ts[(mt * 16 + q4 * 4 + r) * 36 + nh * 16 + lm] = f2bf(y * osc);
          }
      }
      const int dq = h2 * 32 + cgrp;  // lane's first d for the store phase
#pragma unroll
      for (int it = 0; it < 8; it++) {
        const int row = it * 8 + rgrp;
        const short4b v = *(const short4b*)(ts + row * 36 + cgrp);
        *(short4b*)(Dst + ((size_t)(biU * NH_ + hU) * S_ + si0 + row) * HD_ +
                    dq) = v;
      }
    }
  }
}

// ---------------------------------------------------------------------------
// Flash attention on MFMA. Block = (64 q-rows) x (b,h); 4 waves, each owns a
// 16-row q strip. Q frags live in registers across the K loop; K/V frags read
// straight from global (L2-resident). P transposes D-layout -> A-layout via a
// wave-private LDS strip (stride 72 bf16 => 2-way banks only; DS ops are
// in-order per wave so no barriers needed).
// ---------------------------------------------------------------------------
__global__ __launch_bounds__(256) void flash_mfma(
    const unsigned short* __restrict__ Q, const unsigned short* __restrict__ Kg,
    const unsigned short* __restrict__ Vt, const int* __restrict__ lengths,
    unsigned short* __restrict__ Oa) {
  __shared__ __align__(16) unsigned short Ps[4][16 * 72];
  const int bh = blockIdx.y, b = bh >> 4, h = bh & 15;
  const int q0 = blockIdx.x * 64;
  const int w = threadIdx.x >> 6, lane = threadIdx.x & 63;
  const int lm = lane & 15, q4 = lane >> 4;
  const int len = lengths[b];
  const unsigned short* Qp = Q + (size_t)bh * S_ * HD_;
  const unsigned short* Kp = Kg + (size_t)bh * S_ * HD_;
  const unsigned short* Vp = Vt + (size_t)bh * HD_ * S_;

  const int qrow = q0 + w * 16 + lm;  // A-operand row for this lane
  short8 qf[2];
  qf[0] = *(const short8*)(Qp + (size_t)qrow * HD_ + q4 * 8);
  qf[1] = *(const short8*)(Qp + (size_t)qrow * HD_ + 32 + q4 * 8);

  const floatx4 z4 = {0.f, 0.f, 0.f, 0.f};
  floatx4 o[4];
#pragma unroll
  for (int dt = 0; dt < 4; dt++) o[dt] = z4;
  float m_i[4], l_i[4];
#pragma unroll
  for (int r = 0; r < 4; r++) { m_i[r] = -1e30f; l_i[r] = 0.0f; }

  unsigned short* ps = Ps[w];
  const int ktiles = min(q0 / 64 + 1, (len + 63) >> 6);
  for (int kt = 0; kt < ktiles; kt++) {
    const int k0 = kt * 64;
    // S = Q K^T  (64 cols in 4 n-tiles)
    floatx4 sc[4];
#pragma unroll
    for (int nt = 0; nt < 4; nt++) sc[nt] = z4;
#pragma unroll
    for (int nt = 0; nt < 4; nt++) {
      const unsigned short* kb = Kp + (size_t)(k0 + nt * 16 + lm) * HD_;
      const short8 b0 = *(const short8*)(kb + q4 * 8);
      const short8 b1 = *(const short8*)(kb + 32 + q4 * 8);
      sc[nt] = __builtin_amdgcn_mfma_f32_16x16x32_bf16(qf[0], b0, sc[nt], 0, 0, 0);
      sc[nt] = __builtin_amdgcn_mfma_f32_16x16x32_bf16(qf[1], b1, sc[nt], 0, 0, 0);
    }
    // mask (causal + key length); D layout: row=q4*4+r, col=nt*16+lm
#pragma unroll
    for (int nt = 0; nt < 4; nt++) {
      const int col = k0 + nt * 16 + lm;
#pragma unroll
      for (int r = 0; r < 4; r++) {
        const int row = q0 + w * 16 + q4 * 4 + r;
        if (col > row || col >= len) sc[nt][r] = -1e30f;
      }
    }
    // online softmax (row stats live in 16-lane groups)
#pragma unroll
    for (int r = 0; r < 4; r++) {
      float mx = fmaxf(fmaxf(sc[0][r], sc[1][r]), fmaxf(sc[2][r], sc[3][r]));
#pragma unroll
      for (int off = 1; off < 16; off <<= 1) mx = fmaxf(mx, __shfl_xor(mx, off));
      const float mt = fmaxf(m_i[r], mx);
      const float al = __expf(m_i[r] - mt);
      float rs = 0.0f;
#pragma unroll
      for (int nt = 0; nt < 4; nt++) {
        const float pp = __expf(sc[nt][r] - mt);
        sc[nt][r] = pp;
        rs += pp;
      }
#pragma unroll
      for (int off = 1; off < 16; off <<= 1) rs += __shfl_xor(rs, off);
      l_i[r] = l_i[r] * al + rs;
      m_i[r] = mt;
#pragma unroll
      for (int dt = 0; dt < 4; dt++) o[dt][r] *= al;
    }
    // P: D-layout -> bf16 -> wave-private LDS (A-layout source)
#pragma unroll
    for (int nt = 0; nt < 4; nt++)
#pragma unroll
      for (int r = 0; r < 4; r++)
        ps[(q4 * 4 + r) * 72 + nt * 16 + lm] = f2bf(sc[nt][r]);
    // O += P V   (V^T rows are d, k-dim is key)
#pragma unroll
    for (int ks = 0; ks < 2; ks++) {
      const short8 pf = *(const short8*)(ps + lm * 72 + ks * 32 + q4 * 8);
#pragma unroll
      for (int dt = 0; dt < 4; dt++) {
        const short8 vf = *(const short8*)(
            Vp + (size_t)(dt * 16 + lm) * S_ + k0 + ks * 32 + q4 * 8);
        o[dt] = __builtin_amdgcn_mfma_f32_16x16x32_bf16(pf, vf, o[dt], 0, 0, 0);
      }
    }
  }
  // normalize + write attn (B,S,DM) bf16; col = h*64 + d
#pragma unroll
  for (int dt = 0; dt < 4; dt++)
#pragma unroll
    for (int r = 0; r < 4; r++) {
      const int row = q0 + w * 16 + q4 * 4 + r;
      const int col = h * HD_ + dt * 16 + lm;
      Oa[((size_t)b * S_ + row) * DM_ + col] = f2bf(o[dt][r] / l_i[r]);
    }
}

// ---------------------------------------------------------------------------
// Out projection (bf16 MFMA): C[m][n] = sum_k A[m][k] * W[n][k], fp32 out.
// M=4096, N=1024, K=1024.
// ---------------------------------------------------------------------------
__global__ __launch_bounds__(256) void out_gemm(
    const unsigned short* __restrict__ A, const unsigned short* __restrict__ W,
    float* __restrict__ C) {
  __shared__ __align__(16) unsigned short As[128 * 32];
  __shared__ __align__(16) unsigned short Bs[128 * 32];
  const int m0 = blockIdx.y * 128, n0 = blockIdx.x * 128;
  const int w = threadIdx.x >> 6, lane = threadIdx.x & 63;
  const int lm = lane & 15, q4 = lane >> 4;
  const int srow = w * 32;
  const int r_in = lane >> 2, c_in = (lane & 3) * 8;
  const int wr = (w >> 1) * 64, wc = (w & 1) * 64;
  floatx4 acc[4][4];
  const floatx4 z4 = {0.f, 0.f, 0.f, 0.f};
#pragma unroll
  for (int i = 0; i < 4; i++)
#pragma unroll
    for (int j = 0; j < 4; j++) acc[i][j] = z4;

  for (int k0 = 0; k0 < DM_; k0 += 32) {
    gl2lds16(A + (size_t)(m0 + srow + r_in) * DM_ + k0 + c_in, As + srow * 32);
    gl2lds16(A + (size_t)(m0 + srow + 16 + r_in) * DM_ + k0 + c_in,
             As + (srow + 16) * 32);
    gl2lds16(W + (size_t)(n0 + srow + r_in) * DM_ + k0 + c_in, Bs + srow * 32);
    gl2lds16(W + (size_t)(n0 + srow + 16 + r_in) * DM_ + k0 + c_in,
             Bs + (srow + 16) * 32);
    __syncthreads();
    short8 af[4], bf[4];
#pragma unroll
    for (int t = 0; t < 4; t++)
      af[t] = *(const short8*)(As + (wr + t * 16 + lm) * 32 + q4 * 8);
#pragma unroll
    for (int t = 0; t < 4; t++)
      bf[t] = *(const short8*)(Bs + (wc + t * 16 + lm) * 32 + q4 * 8);
#pragma unroll
    for (int i = 0; i < 4; i++)
#pragma unroll
      for (int j = 0; j < 4; j++)
        acc[i][j] =
            __builtin_amdgcn_mfma_f32_16x16x32_bf16(af[i], bf[j], acc[i][j],
                                                    0, 0, 0);
    __syncthreads();
  }
#pragma unroll
  for (int nt = 0; nt < 4; nt++) {
    const int n = n0 + wc + nt * 16 + lm;
#pragma unroll
    for (int mt = 0; mt < 4; mt++)
#pragma unroll
      for (int r = 0; r < 4; r++) {
        const int m = m0 + wr + mt * 16 + q4 * 4 + r;
        C[(size_t)m * DM_ + n] = acc[mt][nt][r];
      }
  }
}

}  // namespace

extern "C" void kernel_launch(void* const* d_in, const int* in_sizes, int n_in,
                              void* d_out, int out_size, void* d_ws, size_t ws_size,
                              hipStream_t stream) {
  const float* hidden = (const float*)d_in[0];          // (2,2048,1024) f32
  const float* w_qkv = (const float*)d_in[1];           // (3072,1024) f32
  const float* w_out = (const float*)d_in[2];           // (1024,1024) f32
  const unsigned char* amask = (const unsigned char*)d_in[3];  // (2,2048) bool
  const int* pos_xyz = (const int*)d_in[5];             // (2,2048,3) i32
  float* out = (float*)d_out;                           // (2,2048,1024) f32

  constexpr size_t NHID = (size_t)B_ * S_ * DM_;        // 4,194,304
  constexpr size_t NWQ = (size_t)3 * DM_ * DM_;         // 3,145,728
  constexpr size_t NWO = (size_t)DM_ * DM_;             // 1,048,576
  constexpr size_t NQKV = (size_t)B_ * NH_ * S_ * HD_;  // 4,194,304

  unsigned short* hb = (unsigned short*)d_ws;
  unsigned short* wqb = hb + NHID;
  unsigned short* wob = wqb + NWQ;
  unsigned short* Qb = wob + NWO;
  unsigned short* Kb = Qb + NQKV;
  unsigned short* Vtb = Kb + NQKV;
  unsigned short* attn = Vtb + NQKV;
  int* lens = (int*)(attn + NQKV);

  cvt_bf16<<<dim3(NHID / 8 / 256), dim3(256), 0, stream>>>(hidden, hb,
                                                           (int)(NHID / 8));
  cvt_bf16<<<dim3(NWQ / 8 / 256), dim3(256), 0, stream>>>(w_qkv, wqb,
                                                          (int)(NWQ / 8));
  cvt_bf16<<<dim3(NWO / 8 / 256), dim3(256), 0, stream>>>(w_out, wob,
                                                          (int)(NWO / 8));
  lengths_kernel<<<dim3(B_), dim3(256), 0, stream>>>(amask, lens);
  qkv_gemm<<<dim3(3 * DM_ / 128, B_ * S_ / 128), dim3(256), 0, stream>>>(
      hb, wqb, pos_xyz, Qb, Kb, Vtb);
  flash_mfma<<<dim3(S_ / 64, B_ * NH_), dim3(256), 0, stream>>>(
      Qb, Kb, Vtb, lens, attn);
  out_gemm<<<dim3(DM_ / 128, B_ * S_ / 128), dim3(256), 0, stream>>>(
      attn, wob, out);
}